// Round 12
// baseline (232.668 us; speedup 1.0000x reference)
//
#include <hip/hip_runtime.h>
#include <cstdint>
#include <cstddef>

#define D_MODEL 1024
#define N_HEADS 16
#define HEAD_DIM 64
#define SEQ 2048
#define BATCH 2

typedef __attribute__((ext_vector_type(8))) short bf16x8;
typedef __attribute__((ext_vector_type(4))) float f32x4;

__device__ inline unsigned short f2bf(float f) {
    union { float f; unsigned u; } v; v.f = f;
    unsigned r = v.u + 0x7fffu + ((v.u >> 16) & 1u);
    return (unsigned short)(r >> 16);
}

// async global->LDS, 16 B per lane; LDS dst must be wave-base + lane*16.
__device__ __forceinline__ void gload_lds16(const unsigned short* g, unsigned short* l) {
    __builtin_amdgcn_global_load_lds(
        (const __attribute__((address_space(1))) unsigned int*)g,
        (__attribute__((address_space(3))) unsigned int*)l, 16, 0, 0);
}

// s_waitcnt immediates (gfx9: vmcnt[3:0]|[15:14], expcnt[6:4], lgkmcnt[11:8])
#define WAITCNT_VM4 0x0F74   // vmcnt(4), expcnt/lgkmcnt = no-wait
#define WAITCNT_VM0 0x0F70   // vmcnt(0)

// ---------------------------------------------------------------------------
// Fused converts: x->bf16 | w_qkv->Wqt (permuted transpose) | w_proj->Wpt.
// ---------------------------------------------------------------------------
__global__ __launch_bounds__(256) void fused_convert_kernel(
    const float* __restrict__ X, unsigned short* __restrict__ Xb,
    const float* __restrict__ Wq, unsigned short* __restrict__ Wqt,
    const float* __restrict__ Wp, unsigned short* __restrict__ Wpt)
{
    const int blk = blockIdx.x;
    const int tid = threadIdx.x;
    __shared__ float t[32][33];

    if (blk < 2048) {
        const int idx = blk * 256 + tid;
        const float4* src = (const float4*)X;
        float4 v0 = src[idx * 2], v1 = src[idx * 2 + 1];
        union { unsigned short u[8]; uint4 v; } o;
        o.u[0] = f2bf(v0.x); o.u[1] = f2bf(v0.y); o.u[2] = f2bf(v0.z); o.u[3] = f2bf(v0.w);
        o.u[4] = f2bf(v1.x); o.u[5] = f2bf(v1.y); o.u[6] = f2bf(v1.z); o.u[7] = f2bf(v1.w);
        ((uint4*)Xb)[idx] = o.v;
    } else if (blk < 5120) {
        const int bb = blk - 2048;
        const int c0 = (bb % 96) * 32, r0 = (bb / 96) * 32;
        const int a = tid & 31, b = tid >> 5;
#pragma unroll
        for (int i = 0; i < 32; i += 8)
            t[b + i][a] = Wq[(size_t)(r0 + b + i) * (3 * D_MODEL) + c0 + a];
        __syncthreads();
#pragma unroll
        for (int i = 0; i < 32; i += 8) {
            const int c = c0 + b + i;
            const int np = (c % 3) * 1024 + c / 3;   // which*1024 + h*64 + d
            Wqt[(size_t)np * D_MODEL + r0 + a] = f2bf(t[a][b + i]);
        }
    } else {
        const int bb = blk - 5120;
        const int c0 = (bb % 32) * 32, r0 = (bb / 32) * 32;
        const int a = tid & 31, b = tid >> 5;
#pragma unroll
        for (int i = 0; i < 32; i += 8)
            t[b + i][a] = Wp[(size_t)(r0 + b + i) * D_MODEL + c0 + a];
        __syncthreads();
#pragma unroll
        for (int i = 0; i < 32; i += 8)
            Wpt[(size_t)(c0 + b + i) * D_MODEL + r0 + a] = f2bf(t[a][b + i]);
    }
}

// ---------------------------------------------------------------------------
// V[bh][n][d] -> Vt[bh][d][n], 64x64 bf16 tiles through LDS.
// ---------------------------------------------------------------------------
__global__ __launch_bounds__(256) void v_transpose(
    const unsigned short* __restrict__ V, unsigned short* __restrict__ Vt)
{
    const int n0 = blockIdx.x * 64;
    const int bh = blockIdx.y;
    __shared__ unsigned short t[64 * 72];
    const int tid = threadIdx.x;
    const uint4* src = (const uint4*)(V + ((size_t)bh * SEQ + n0) * HEAD_DIM);
#pragma unroll
    for (int it = 0; it < 2; it++) {
        const int lin = tid + it * 256;
        const int row = lin >> 3, p = lin & 7;
        ((uint4*)t)[row * 9 + p] = src[lin];
    }
    __syncthreads();
#pragma unroll
    for (int it = 0; it < 2; it++) {
        const int lin = tid + it * 256;
        const int drow = lin >> 3, p = lin & 7;
        union { unsigned short u[8]; uint4 v; } o;
#pragma unroll
        for (int e = 0; e < 8; e++) o.u[e] = t[(p * 8 + e) * 72 + drow];
        ((uint4*)(Vt + ((size_t)bh * HEAD_DIM + drow) * SEQ + n0))[p] = o.v;
    }
}

// ---------------------------------------------------------------------------
// Pipelined GEMM core (R11-proven): 128x128 tile, BK=32, triple-buffer LDS,
// stage depth 2, raw s_barrier + explicit vmcnt. LDS 48 KB -> 3 blocks/CU.
// ---------------------------------------------------------------------------
#define GEMM_PIPE3_BODY(A_, B_, KBASE, NITER)                                  \
    const int tid = threadIdx.x;                                               \
    const int w = tid >> 6, lane = tid & 63;                                   \
    const int l15 = lane & 15, quad = lane >> 4;                               \
    const int wr = w >> 1, wc = w & 1;                                         \
    const int row0 = blockIdx.y * 128, col0 = blockIdx.x * 128;                \
    __shared__ unsigned short As[3][4096];                                     \
    __shared__ unsigned short Bs[3][4096];                                     \
    const f32x4 zero4 = {0.f, 0.f, 0.f, 0.f};                                  \
    f32x4 acc[4][4];                                                           \
    _Pragma("unroll") for (int i = 0; i < 4; i++)                              \
        _Pragma("unroll") for (int j = 0; j < 4; j++) acc[i][j] = zero4;       \
    auto stage_ = [&](int sb_, int kt_) {                                      \
        const int k0 = (KBASE) + kt_ * 32 + quad * 8;                          \
        _Pragma("unroll") for (int i = 0; i < 2; i++) {                        \
            const int f = w * 2 + i;                                           \
            gload_lds16((A_) + (size_t)(row0 + f * 16 + l15) * D_MODEL + k0,   \
                        &As[sb_][f * 512 + lane * 8]);                         \
            gload_lds16((B_) + (size_t)(col0 + f * 16 + l15) * D_MODEL + k0,   \
                        &Bs[sb_][f * 512 + lane * 8]);                         \
        }                                                                      \
    };                                                                         \
    stage_(0, 0);                                                              \
    stage_(1, 1);                                                              \
    int sb = 0;                                                                \
    for (int kt = 0; kt < (NITER); kt++) {                                     \
        if (kt < (NITER) - 1) {                                                \
            __builtin_amdgcn_s_waitcnt(WAITCNT_VM4);                           \
            __builtin_amdgcn_s_barrier();                                      \
            if (kt + 2 < (NITER)) stage_((sb + 2 > 2) ? sb - 1 : sb + 2, kt + 2); \
        } else {                                                               \
            __builtin_amdgcn_s_waitcnt(WAITCNT_VM0);                           \
            __builtin_amdgcn_s_barrier();                                      \
        }                                                                      \
        bf16x8 af[4], bfr[4];                                                  \
        _Pragma("unroll") for (int i = 0; i < 4; i++)                          \
            af[i] = *(const bf16x8*)&As[sb][(wr * 4 + i) * 512 + lane * 8];    \
        _Pragma("unroll") for (int j = 0; j < 4; j++)                          \
            bfr[j] = *(const bf16x8*)&Bs[sb][(wc * 4 + j) * 512 + lane * 8];   \
        _Pragma("unroll") for (int i = 0; i < 4; i++)                          \
            _Pragma("unroll") for (int j = 0; j < 4; j++)                      \
                acc[i][j] = __builtin_amdgcn_mfma_f32_16x16x32_bf16(           \
                    af[i], bfr[j], acc[i][j], 0, 0, 0);                        \
        sb = (sb == 2) ? 0 : sb + 1;                                           \
    }

// GEMM1: Xb @ Wqt^T -> Q/K/V bf16. Q is PRE-SCALED by 0.125 (softmax scale)
// so the flash kernel's hot loop drops 16 mults/iter.
__global__ __launch_bounds__(256) void gemm_qkv_mfma(
    const unsigned short* __restrict__ A, const unsigned short* __restrict__ B,
    unsigned short* __restrict__ Q, unsigned short* __restrict__ Kq,
    unsigned short* __restrict__ Vb)
{
    GEMM_PIPE3_BODY(A, B, 0, 32)
    const int nbase = col0 + wc * 64;              // wave-uniform, mult of 64
    const int which = nbase >> 10;
    unsigned short* const dst = (which == 0) ? Q : (which == 1) ? Kq : Vb;
    const float oscale = (which == 0) ? 0.125f : 1.0f;
#pragma unroll
    for (int i = 0; i < 4; i++) {
#pragma unroll
        for (int r = 0; r < 4; r++) {
            const int row = row0 + wr * 64 + i * 16 + quad * 4 + r;
            const int bb = row >> 11, n = row & (SEQ - 1);
#pragma unroll
            for (int j = 0; j < 4; j++) {
                const int idx = (nbase + j * 16 + l15) & 1023;  // h*64+d
                const int h = idx >> 6, dd = idx & 63;
                dst[(((size_t)(bb * N_HEADS + h)) * SEQ + n) * HEAD_DIM + dd] =
                    f2bf(acc[i][j][r] * oscale);
            }
        }
    }
}

// GEMM2: SPLIT-K=2, pipelined. Grid (8, 32, 2). K=512/block, NITER=16.
__global__ __launch_bounds__(256) void gemm_proj_splitk(
    const unsigned short* __restrict__ A, const unsigned short* __restrict__ B,
    float* __restrict__ P)
{
    const int kbase = blockIdx.z * 512;
    GEMM_PIPE3_BODY(A, B, kbase, 16)
    float* const dst = P + (size_t)blockIdx.z * (4096ull * 1024ull);
#pragma unroll
    for (int i = 0; i < 4; i++) {
#pragma unroll
        for (int r = 0; r < 4; r++) {
            const int row = row0 + wr * 64 + i * 16 + quad * 4 + r;
#pragma unroll
            for (int j = 0; j < 4; j++) {
                const int c = col0 + wc * 64 + j * 16 + l15;
                dst[(size_t)row * D_MODEL + c] = acc[i][j][r];
            }
        }
    }
}

// out = P0 + P1 (fp32). 4M floats = 1M float4; 1024 blocks x 256 thr x 4.
__global__ __launch_bounds__(256) void add_out_kernel(
    const float* __restrict__ P, float* __restrict__ out)
{
    const float4* p0 = (const float4*)P;
    const float4* p1 = (const float4*)(P + 4096ull * 1024ull);
    float4* o = (float4*)out;
    const int base = (blockIdx.x * 256 + threadIdx.x) * 4;
#pragma unroll
    for (int j = 0; j < 4; j++) {
        float4 a = p0[base + j], b = p1[base + j];
        float4 r = {a.x + b.x, a.y + b.y, a.z + b.z, a.w + b.w};
        o[base + j] = r;
    }
}

// ---------------------------------------------------------------------------
// Flash attention v3: S^T trick + register Q (pre-scaled) + TRIPLE-buffered
// K/V with the R11 vmcnt/s_barrier pipeline + frag-order Ps (conflict-free).
//
// Ps frag-order: element P[query=m][key=k] at kh*512 + quadk*128 + m*8 + (k&7)
// (kh=k>>5, quadk=(k>>3)&3). Producer (S^T lane l15=query, key=ct*16+quad*4+r)
// writes 4 shorts (uint2); PV reads the standard b128 A-frag pattern.
// LDS: 3*8K (Ks) + 3*8K (Vs) + 8K (Ps) = 56 KB -> 2 blocks/CU.
// ---------------------------------------------------------------------------
__global__ __launch_bounds__(256) void flash_attn_kernel(
    const unsigned short* __restrict__ Q,
    const unsigned short* __restrict__ K,
    const unsigned short* __restrict__ Vt,
    unsigned short* __restrict__ O)
{
    const int idx = blockIdx.x;
    const int bh = idx & 31;
    const int qt2 = idx >> 5;
    const int hi = qt2 >> 3, lo = qt2 & 7;
    const int qt = (hi == 0) ? lo : (hi == 1) ? 31 - lo : (hi == 2) ? lo + 8 : 23 - lo;

    const int tid = threadIdx.x;
    const int w = tid >> 6, lane = tid & 63;
    const int l15 = lane & 15, quad = lane >> 4;

    __shared__ unsigned short Ks[3][4096];
    __shared__ unsigned short Vs[3][4096];
    __shared__ unsigned short Ps[4][1024];

    bf16x8 qf[2];
    {
        const unsigned short* qrow =
            Q + ((size_t)bh * SEQ + qt * 64 + w * 16 + l15) * HEAD_DIM;
        qf[0] = *(const bf16x8*)(qrow + quad * 8);
        qf[1] = *(const bf16x8*)(qrow + 32 + quad * 8);
    }

    const f32x4 zero4 = {0.f, 0.f, 0.f, 0.f};
    f32x4 o_acc[4] = {zero4, zero4, zero4, zero4};
    float m_i = -1e30f, l_i = 0.f;

    auto stage = [&](int slot, int kt_t) {
        const int key0 = kt_t * 64;
#pragma unroll
        for (int i = 0; i < 2; i++) {
            const int f = w * 2 + i;
            const int ct = f >> 1, kh = f & 1;
            gload_lds16(K + ((size_t)bh * SEQ + key0 + ct * 16 + l15) * HEAD_DIM
                          + kh * 32 + quad * 8,
                        &Ks[slot][f * 512 + lane * 8]);
            gload_lds16(Vt + ((size_t)bh * HEAD_DIM + ct * 16 + l15) * SEQ
                           + key0 + kh * 32 + quad * 8,
                        &Vs[slot][f * 512 + lane * 8]);
        }
    };

    stage(0, 0);
    if (qt > 0) stage(1, 1);
    int sl = 0;

    const int qg = qt * 64 + w * 16 + l15;

    for (int kt = 0; kt <= qt; kt++) {
        if (kt < qt) {
            __builtin_amdgcn_s_waitcnt(WAITCNT_VM4);   // tile kt drained; kt+1 in flight
            __builtin_amdgcn_s_barrier();
            if (kt + 2 <= qt) stage((sl + 2 > 2) ? sl - 1 : sl + 2, kt + 2);
        } else {
            __builtin_amdgcn_s_waitcnt(WAITCNT_VM0);
            __builtin_amdgcn_s_barrier();
        }

        // ---- S^T = K Q^T (Q pre-scaled by 0.125) ----
        f32x4 st[4] = {zero4, zero4, zero4, zero4};
#pragma unroll
        for (int kh = 0; kh < 2; kh++) {
#pragma unroll
            for (int ct = 0; ct < 4; ct++) {
                bf16x8 kf = *(const bf16x8*)&Ks[sl][(ct * 2 + kh) * 512 + lane * 8];
                st[ct] = __builtin_amdgcn_mfma_f32_16x16x32_bf16(kf, qf[kh], st[ct], 0, 0, 0);
            }
        }

        // ---- causal mask (diag tile only) + per-query max ----
        const bool diag = (kt == qt);
        float mt = -1e30f;
#pragma unroll
        for (int ct = 0; ct < 4; ct++) {
#pragma unroll
            for (int r = 0; r < 4; r++) {
                float v = st[ct][r];
                const int kg = kt * 64 + ct * 16 + quad * 4 + r;
                if (diag && kg > qg) v = -1e30f;
                st[ct][r] = v;
                mt = fmaxf(mt, v);
            }
        }
        mt = fmaxf(mt, __shfl_xor(mt, 16));
        mt = fmaxf(mt, __shfl_xor(mt, 32));

        const float mn = fmaxf(m_i, mt);
        const float alpha = __expf(m_i - mn);
        m_i = mn;

        // ---- p = exp(s-m); write frag-order Ps (uint2, ~2-way banks) ----
        float ls = 0.f;
#pragma unroll
        for (int ct = 0; ct < 4; ct++) {
            union { unsigned short u[4]; uint2 v; } pk;
#pragma unroll
            for (int r = 0; r < 4; r++) {
                float p = __expf(st[ct][r] - mn);
                ls += p;
                pk.u[r] = f2bf(p);
            }
            const int addr = (ct >> 1) * 512 + ((ct & 1) * 2 + (quad >> 1)) * 128
                           + l15 * 8 + (quad & 1) * 4;
            *(uint2*)&Ps[w][addr] = pk.v;
        }
        ls += __shfl_xor(ls, 16);
        ls += __shfl_xor(ls, 32);
        l_i = l_i * alpha + ls;

        // ---- rescale O: alpha per O-row (query quad*4+r) via shfl ----
        float ar[4];
#pragma unroll
        for (int r = 0; r < 4; r++)
            ar[r] = __shfl(alpha, (lane & 48) | (quad * 4 + r));
#pragma unroll
        for (int dt = 0; dt < 4; dt++)
#pragma unroll
            for (int r = 0; r < 4; r++)
                o_acc[dt][r] *= ar[r];

        // ---- O += P V (A-frag = standard b128 pattern from Ps) ----
#pragma unroll
        for (int kh = 0; kh < 2; kh++) {
            bf16x8 pa = *(const bf16x8*)&Ps[w][kh * 512 + quad * 128 + l15 * 8];
#pragma unroll
            for (int dt = 0; dt < 4; dt++) {
                bf16x8 vf = *(const bf16x8*)&Vs[sl][(dt * 2 + kh) * 512 + lane * 8];
                o_acc[dt] = __builtin_amdgcn_mfma_f32_16x16x32_bf16(pa, vf, o_acc[dt], 0, 0, 0);
            }
        }
        sl = (sl == 2) ? 0 : sl + 1;
    }

    const float linv = 1.0f / l_i;
    float lr[4];
#pragma unroll
    for (int r = 0; r < 4; r++)
        lr[r] = __shfl(linv, (lane & 48) | (quad * 4 + r));

    const int b = bh >> 4, h = bh & 15;
#pragma unroll
    for (int r = 0; r < 4; r++) {
        const int q = qt * 64 + w * 16 + quad * 4 + r;
        unsigned short* orow = O + ((size_t)b * SEQ + q) * D_MODEL + h * HEAD_DIM;
#pragma unroll
        for (int dt = 0; dt < 4; dt++)
            orow[dt * 16 + l15] = f2bf(o_acc[dt][r] * lr[r]);
    }
}

// ---------------------------------------------------------------------------
extern "C" void kernel_launch(void* const* d_in, const int* in_sizes, int n_in,
                              void* d_out, int out_size, void* d_ws, size_t ws_size,
                              hipStream_t stream) {
    const float* x      = (const float*)d_in[0];
    const float* w_qkv  = (const float*)d_in[1];
    const float* w_proj = (const float*)d_in[2];
    float* out = (float*)d_out;

    unsigned short* Xb  = (unsigned short*)d_ws;          // 4M shorts
    unsigned short* Wqt = Xb  + (size_t)4 * 1024 * 1024;  // 3M
    unsigned short* Wpt = Wqt + (size_t)3 * 1024 * 1024;  // 1M
    unsigned short* Qb  = Wpt + (size_t)1 * 1024 * 1024;  // 4M
    unsigned short* Kb  = Qb  + (size_t)4 * 1024 * 1024;  // 4M
    unsigned short* Vb  = Kb  + (size_t)4 * 1024 * 1024;  // 4M (untransposed)
    unsigned short* Vtb = Vb  + (size_t)4 * 1024 * 1024;  // 4M
    unsigned short* Ob  = Vtb + (size_t)4 * 1024 * 1024;  // 4M  (56 MB total)

    // Split-K partials alias Qb..Vtb (32 MB, dead after flash):
    // P0 = Qb..Kb (16 MB), P1 = Vb..Vtb (16 MB), contiguous.
    float* Pp = (float*)Qb;

    fused_convert_kernel<<<dim3(6144), 256, 0, stream>>>(
        x, Xb, w_qkv, Wqt, w_proj, Wpt);

    gemm_qkv_mfma<<<dim3(3 * D_MODEL / 128, BATCH * SEQ / 128), 256, 0, stream>>>(
        Xb, Wqt, Qb, Kb, Vb);

    v_transpose<<<dim3(SEQ / 64, BATCH * N_HEADS), 256, 0, stream>>>(Vb, Vtb);

    flash_attn_kernel<<<dim3(SEQ / 64 * BATCH * N_HEADS), 256, 0, stream>>>(
        Qb, Kb, Vtb, Ob);

    gemm_proj_splitk<<<dim3(D_MODEL / 128, BATCH * SEQ / 128, 2), 256, 0, stream>>>(
        Ob, Wpt, Pp);

    add_out_kernel<<<dim3(1024), 256, 0, stream>>>(Pp, out);
}

// Round 13
// 218.153 us; speedup vs baseline: 1.0665x; 1.0665x over previous
//
#include <hip/hip_runtime.h>
#include <cstdint>
#include <cstddef>

#define D_MODEL 1024
#define N_HEADS 16
#define HEAD_DIM 64
#define SEQ 2048
#define BATCH 2

typedef __attribute__((ext_vector_type(8))) short bf16x8;
typedef __attribute__((ext_vector_type(4))) float f32x4;

__device__ inline unsigned short f2bf(float f) {
    union { float f; unsigned u; } v; v.f = f;
    unsigned r = v.u + 0x7fffu + ((v.u >> 16) & 1u);
    return (unsigned short)(r >> 16);
}

// async global->LDS, 16 B per lane; LDS dst must be wave-base + lane*16.
__device__ __forceinline__ void gload_lds16(const unsigned short* g, unsigned short* l) {
    __builtin_amdgcn_global_load_lds(
        (const __attribute__((address_space(1))) unsigned int*)g,
        (__attribute__((address_space(3))) unsigned int*)l, 16, 0, 0);
}

// s_waitcnt immediates (gfx9: vmcnt[3:0]|[15:14], expcnt[6:4], lgkmcnt[11:8])
#define WAITCNT_VM4 0x0F74   // vmcnt(4), expcnt/lgkmcnt = no-wait
#define WAITCNT_VM0 0x0F70   // vmcnt(0)

// ---------------------------------------------------------------------------
// Fused converts: x->bf16 | w_qkv->Wqt (permuted transpose) | w_proj->Wpt.
// ---------------------------------------------------------------------------
__global__ __launch_bounds__(256) void fused_convert_kernel(
    const float* __restrict__ X, unsigned short* __restrict__ Xb,
    const float* __restrict__ Wq, unsigned short* __restrict__ Wqt,
    const float* __restrict__ Wp, unsigned short* __restrict__ Wpt)
{
    const int blk = blockIdx.x;
    const int tid = threadIdx.x;
    __shared__ float t[32][33];

    if (blk < 2048) {
        const int idx = blk * 256 + tid;
        const float4* src = (const float4*)X;
        float4 v0 = src[idx * 2], v1 = src[idx * 2 + 1];
        union { unsigned short u[8]; uint4 v; } o;
        o.u[0] = f2bf(v0.x); o.u[1] = f2bf(v0.y); o.u[2] = f2bf(v0.z); o.u[3] = f2bf(v0.w);
        o.u[4] = f2bf(v1.x); o.u[5] = f2bf(v1.y); o.u[6] = f2bf(v1.z); o.u[7] = f2bf(v1.w);
        ((uint4*)Xb)[idx] = o.v;
    } else if (blk < 5120) {
        const int bb = blk - 2048;
        const int c0 = (bb % 96) * 32, r0 = (bb / 96) * 32;
        const int a = tid & 31, b = tid >> 5;
#pragma unroll
        for (int i = 0; i < 32; i += 8)
            t[b + i][a] = Wq[(size_t)(r0 + b + i) * (3 * D_MODEL) + c0 + a];
        __syncthreads();
#pragma unroll
        for (int i = 0; i < 32; i += 8) {
            const int c = c0 + b + i;
            const int np = (c % 3) * 1024 + c / 3;   // which*1024 + h*64 + d
            Wqt[(size_t)np * D_MODEL + r0 + a] = f2bf(t[a][b + i]);
        }
    } else {
        const int bb = blk - 5120;
        const int c0 = (bb % 32) * 32, r0 = (bb / 32) * 32;
        const int a = tid & 31, b = tid >> 5;
#pragma unroll
        for (int i = 0; i < 32; i += 8)
            t[b + i][a] = Wp[(size_t)(r0 + b + i) * D_MODEL + c0 + a];
        __syncthreads();
#pragma unroll
        for (int i = 0; i < 32; i += 8)
            Wpt[(size_t)(c0 + b + i) * D_MODEL + r0 + a] = f2bf(t[a][b + i]);
    }
}

// ---------------------------------------------------------------------------
// V[bh][n][d] -> Vt[bh][d][n], 64x64 bf16 tiles through LDS.
// ---------------------------------------------------------------------------
__global__ __launch_bounds__(256) void v_transpose(
    const unsigned short* __restrict__ V, unsigned short* __restrict__ Vt)
{
    const int n0 = blockIdx.x * 64;
    const int bh = blockIdx.y;
    __shared__ unsigned short t[64 * 72];
    const int tid = threadIdx.x;
    const uint4* src = (const uint4*)(V + ((size_t)bh * SEQ + n0) * HEAD_DIM);
#pragma unroll
    for (int it = 0; it < 2; it++) {
        const int lin = tid + it * 256;
        const int row = lin >> 3, p = lin & 7;
        ((uint4*)t)[row * 9 + p] = src[lin];
    }
    __syncthreads();
#pragma unroll
    for (int it = 0; it < 2; it++) {
        const int lin = tid + it * 256;
        const int drow = lin >> 3, p = lin & 7;
        union { unsigned short u[8]; uint4 v; } o;
#pragma unroll
        for (int e = 0; e < 8; e++) o.u[e] = t[(p * 8 + e) * 72 + drow];
        ((uint4*)(Vt + ((size_t)bh * HEAD_DIM + drow) * SEQ + n0))[p] = o.v;
    }
}

// ---------------------------------------------------------------------------
// Pipelined GEMM core (R11-proven): 128x128 tile, BK=32, triple-buffer LDS,
// stage depth 2, raw s_barrier + explicit vmcnt. LDS 48 KB -> 3 blocks/CU.
// ---------------------------------------------------------------------------
#define GEMM_PIPE3_BODY(A_, B_, KBASE, NITER)                                  \
    const int tid = threadIdx.x;                                               \
    const int w = tid >> 6, lane = tid & 63;                                   \
    const int l15 = lane & 15, quad = lane >> 4;                               \
    const int wr = w >> 1, wc = w & 1;                                         \
    const int row0 = blockIdx.y * 128, col0 = blockIdx.x * 128;                \
    __shared__ unsigned short As[3][4096];                                     \
    __shared__ unsigned short Bs[3][4096];                                     \
    const f32x4 zero4 = {0.f, 0.f, 0.f, 0.f};                                  \
    f32x4 acc[4][4];                                                           \
    _Pragma("unroll") for (int i = 0; i < 4; i++)                              \
        _Pragma("unroll") for (int j = 0; j < 4; j++) acc[i][j] = zero4;       \
    auto stage_ = [&](int sb_, int kt_) {                                      \
        const int k0 = (KBASE) + kt_ * 32 + quad * 8;                          \
        _Pragma("unroll") for (int i = 0; i < 2; i++) {                        \
            const int f = w * 2 + i;                                           \
            gload_lds16((A_) + (size_t)(row0 + f * 16 + l15) * D_MODEL + k0,   \
                        &As[sb_][f * 512 + lane * 8]);                         \
            gload_lds16((B_) + (size_t)(col0 + f * 16 + l15) * D_MODEL + k0,   \
                        &Bs[sb_][f * 512 + lane * 8]);                         \
        }                                                                      \
    };                                                                         \
    stage_(0, 0);                                                              \
    stage_(1, 1);                                                              \
    int sb = 0;                                                                \
    for (int kt = 0; kt < (NITER); kt++) {                                     \
        if (kt < (NITER) - 1) {                                                \
            __builtin_amdgcn_s_waitcnt(WAITCNT_VM4);                           \
            __builtin_amdgcn_s_barrier();                                      \
            if (kt + 2 < (NITER)) stage_((sb + 2 > 2) ? sb - 1 : sb + 2, kt + 2); \
        } else {                                                               \
            __builtin_amdgcn_s_waitcnt(WAITCNT_VM0);                           \
            __builtin_amdgcn_s_barrier();                                      \
        }                                                                      \
        bf16x8 af[4], bfr[4];                                                  \
        _Pragma("unroll") for (int i = 0; i < 4; i++)                          \
            af[i] = *(const bf16x8*)&As[sb][(wr * 4 + i) * 512 + lane * 8];    \
        _Pragma("unroll") for (int j = 0; j < 4; j++)                          \
            bfr[j] = *(const bf16x8*)&Bs[sb][(wc * 4 + j) * 512 + lane * 8];   \
        _Pragma("unroll") for (int i = 0; i < 4; i++)                          \
            _Pragma("unroll") for (int j = 0; j < 4; j++)                      \
                acc[i][j] = __builtin_amdgcn_mfma_f32_16x16x32_bf16(           \
                    af[i], bfr[j], acc[i][j], 0, 0, 0);                        \
        sb = (sb == 2) ? 0 : sb + 1;                                           \
    }

// GEMM1: Xb @ Wqt^T -> Q/K/V bf16. Q PRE-SCALED by 0.125 (softmax scale).
__global__ __launch_bounds__(256) void gemm_qkv_mfma(
    const unsigned short* __restrict__ A, const unsigned short* __restrict__ B,
    unsigned short* __restrict__ Q, unsigned short* __restrict__ Kq,
    unsigned short* __restrict__ Vb)
{
    GEMM_PIPE3_BODY(A, B, 0, 32)
    const int nbase = col0 + wc * 64;              // wave-uniform, mult of 64
    const int which = nbase >> 10;
    unsigned short* const dst = (which == 0) ? Q : (which == 1) ? Kq : Vb;
    const float oscale = (which == 0) ? 0.125f : 1.0f;
#pragma unroll
    for (int i = 0; i < 4; i++) {
#pragma unroll
        for (int r = 0; r < 4; r++) {
            const int row = row0 + wr * 64 + i * 16 + quad * 4 + r;
            const int bb = row >> 11, n = row & (SEQ - 1);
#pragma unroll
            for (int j = 0; j < 4; j++) {
                const int idx = (nbase + j * 16 + l15) & 1023;  // h*64+d
                const int h = idx >> 6, dd = idx & 63;
                dst[(((size_t)(bb * N_HEADS + h)) * SEQ + n) * HEAD_DIM + dd] =
                    f2bf(acc[i][j][r] * oscale);
            }
        }
    }
}

// GEMM2: SPLIT-K=2, pipelined. Grid (8, 32, 2). K=512/block, NITER=16.
__global__ __launch_bounds__(256) void gemm_proj_splitk(
    const unsigned short* __restrict__ A, const unsigned short* __restrict__ B,
    float* __restrict__ P)
{
    const int kbase = blockIdx.z * 512;
    GEMM_PIPE3_BODY(A, B, kbase, 16)
    float* const dst = P + (size_t)blockIdx.z * (4096ull * 1024ull);
#pragma unroll
    for (int i = 0; i < 4; i++) {
#pragma unroll
        for (int r = 0; r < 4; r++) {
            const int row = row0 + wr * 64 + i * 16 + quad * 4 + r;
#pragma unroll
            for (int j = 0; j < 4; j++) {
                const int c = col0 + wc * 64 + j * 16 + l15;
                dst[(size_t)row * D_MODEL + c] = acc[i][j][r];
            }
        }
    }
}

// out = P0 + P1 (fp32). 4M floats = 1M float4; 1024 blocks x 256 thr x 4.
__global__ __launch_bounds__(256) void add_out_kernel(
    const float* __restrict__ P, float* __restrict__ out)
{
    const float4* p0 = (const float4*)P;
    const float4* p1 = (const float4*)(P + 4096ull * 1024ull);
    float4* o = (float4*)out;
    const int base = (blockIdx.x * 256 + threadIdx.x) * 4;
#pragma unroll
    for (int j = 0; j < 4; j++) {
        float4 a = p0[base + j], b = p1[base + j];
        float4 r = {a.x + b.x, a.y + b.y, a.z + b.z, a.w + b.w};
        o[base + j] = r;
    }
}

// ---------------------------------------------------------------------------
// Flash attention v4: R11 double-buffered __syncthreads staging (TLP-friendly)
// + frag-order Ps (8 KB, low-conflict) + pre-scaled Q.
// LDS: 2*8K (Ks) + 2*8K (Vs) + 8K (Ps) = 40 KB -> exactly 4 blocks/CU;
// 1024 blocks all resident, 16 waves/CU.
//
// Ps frag-order: P[query=m][key=k] at kh*512 + quadk*128 + m*8 + (k&7)
// (kh=k>>5, quadk=(k>>3)&3). Producer (lane l15=query, key=ct*16+quad*4+r)
// writes one uint2 per ct; PV reads the standard b128 A-frag pattern.
// ---------------------------------------------------------------------------
__global__ __launch_bounds__(256) void flash_attn_kernel(
    const unsigned short* __restrict__ Q,
    const unsigned short* __restrict__ K,
    const unsigned short* __restrict__ Vt,
    unsigned short* __restrict__ O)
{
    const int idx = blockIdx.x;
    const int bh = idx & 31;
    const int qt2 = idx >> 5;
    const int hi = qt2 >> 3, lo = qt2 & 7;
    const int qt = (hi == 0) ? lo : (hi == 1) ? 31 - lo : (hi == 2) ? lo + 8 : 23 - lo;

    const int tid = threadIdx.x;
    const int w = tid >> 6, lane = tid & 63;
    const int l15 = lane & 15, quad = lane >> 4;

    __shared__ unsigned short Ks[2][4096];
    __shared__ unsigned short Vs[2][4096];
    __shared__ unsigned short Ps[4][1024];

    bf16x8 qf[2];
    {
        const unsigned short* qrow =
            Q + ((size_t)bh * SEQ + qt * 64 + w * 16 + l15) * HEAD_DIM;
        qf[0] = *(const bf16x8*)(qrow + quad * 8);
        qf[1] = *(const bf16x8*)(qrow + 32 + quad * 8);
    }

    const f32x4 zero4 = {0.f, 0.f, 0.f, 0.f};
    f32x4 o_acc[4] = {zero4, zero4, zero4, zero4};
    float m_i = -1e30f, l_i = 0.f;

    auto stage = [&](int bf, int kt_t) {
        const int key0 = kt_t * 64;
#pragma unroll
        for (int i = 0; i < 2; i++) {
            const int f = w * 2 + i;
            const int ct = f >> 1, kh = f & 1;
            gload_lds16(K + ((size_t)bh * SEQ + key0 + ct * 16 + l15) * HEAD_DIM
                          + kh * 32 + quad * 8,
                        &Ks[bf][f * 512 + lane * 8]);
            gload_lds16(Vt + ((size_t)bh * HEAD_DIM + ct * 16 + l15) * SEQ
                           + key0 + kh * 32 + quad * 8,
                        &Vs[bf][f * 512 + lane * 8]);
        }
    };

    stage(0, 0);
    int buf = 0;

    const int qg = qt * 64 + w * 16 + l15;

    for (int kt = 0; kt <= qt; kt++) {
        __syncthreads();
        if (kt < qt) stage(buf ^ 1, kt + 1);

        // ---- S^T = K Q^T (Q pre-scaled by 0.125) ----
        f32x4 st[4] = {zero4, zero4, zero4, zero4};
#pragma unroll
        for (int kh = 0; kh < 2; kh++) {
#pragma unroll
            for (int ct = 0; ct < 4; ct++) {
                bf16x8 kf = *(const bf16x8*)&Ks[buf][(ct * 2 + kh) * 512 + lane * 8];
                st[ct] = __builtin_amdgcn_mfma_f32_16x16x32_bf16(kf, qf[kh], st[ct], 0, 0, 0);
            }
        }

        // ---- causal mask (diag tile only) + per-query max ----
        const bool diag = (kt == qt);
        float mt = -1e30f;
#pragma unroll
        for (int ct = 0; ct < 4; ct++) {
#pragma unroll
            for (int r = 0; r < 4; r++) {
                float v = st[ct][r];
                const int kg = kt * 64 + ct * 16 + quad * 4 + r;
                if (diag && kg > qg) v = -1e30f;
                st[ct][r] = v;
                mt = fmaxf(mt, v);
            }
        }
        mt = fmaxf(mt, __shfl_xor(mt, 16));
        mt = fmaxf(mt, __shfl_xor(mt, 32));

        const float mn = fmaxf(m_i, mt);
        const float alpha = __expf(m_i - mn);
        m_i = mn;

        // ---- p = exp(s-m); write frag-order Ps (uint2) ----
        float ls = 0.f;
#pragma unroll
        for (int ct = 0; ct < 4; ct++) {
            union { unsigned short u[4]; uint2 v; } pk;
#pragma unroll
            for (int r = 0; r < 4; r++) {
                float p = __expf(st[ct][r] - mn);
                ls += p;
                pk.u[r] = f2bf(p);
            }
            const int addr = (ct >> 1) * 512 + ((ct & 1) * 2 + (quad >> 1)) * 128
                           + l15 * 8 + (quad & 1) * 4;
            *(uint2*)&Ps[w][addr] = pk.v;
        }
        ls += __shfl_xor(ls, 16);
        ls += __shfl_xor(ls, 32);
        l_i = l_i * alpha + ls;

        // ---- rescale O: alpha per O-row (query quad*4+r) via shfl ----
        float ar[4];
#pragma unroll
        for (int r = 0; r < 4; r++)
            ar[r] = __shfl(alpha, (lane & 48) | (quad * 4 + r));
#pragma unroll
        for (int dt = 0; dt < 4; dt++)
#pragma unroll
            for (int r = 0; r < 4; r++)
                o_acc[dt][r] *= ar[r];

        // ---- O += P V (A-frag = standard b128 pattern from Ps) ----
#pragma unroll
        for (int kh = 0; kh < 2; kh++) {
            bf16x8 pa = *(const bf16x8*)&Ps[w][kh * 512 + quad * 128 + l15 * 8];
#pragma unroll
            for (int dt = 0; dt < 4; dt++) {
                bf16x8 vf = *(const bf16x8*)&Vs[buf][(dt * 2 + kh) * 512 + lane * 8];
                o_acc[dt] = __builtin_amdgcn_mfma_f32_16x16x32_bf16(pa, vf, o_acc[dt], 0, 0, 0);
            }
        }
        buf ^= 1;
    }

    const float linv = 1.0f / l_i;
    float lr[4];
#pragma unroll
    for (int r = 0; r < 4; r++)
        lr[r] = __shfl(linv, (lane & 48) | (quad * 4 + r));

    const int b = bh >> 4, h = bh & 15;
#pragma unroll
    for (int r = 0; r < 4; r++) {
        const int q = qt * 64 + w * 16 + quad * 4 + r;
        unsigned short* orow = O + ((size_t)b * SEQ + q) * D_MODEL + h * HEAD_DIM;
#pragma unroll
        for (int dt = 0; dt < 4; dt++)
            orow[dt * 16 + l15] = f2bf(o_acc[dt][r] * lr[r]);
    }
}

// ---------------------------------------------------------------------------
extern "C" void kernel_launch(void* const* d_in, const int* in_sizes, int n_in,
                              void* d_out, int out_size, void* d_ws, size_t ws_size,
                              hipStream_t stream) {
    const float* x      = (const float*)d_in[0];
    const float* w_qkv  = (const float*)d_in[1];
    const float* w_proj = (const float*)d_in[2];
    float* out = (float*)d_out;

    unsigned short* Xb  = (unsigned short*)d_ws;          // 4M shorts
    unsigned short* Wqt = Xb  + (size_t)4 * 1024 * 1024;  // 3M
    unsigned short* Wpt = Wqt + (size_t)3 * 1024 * 1024;  // 1M
    unsigned short* Qb  = Wpt + (size_t)1 * 1024 * 1024;  // 4M
    unsigned short* Kb  = Qb  + (size_t)4 * 1024 * 1024;  // 4M
    unsigned short* Vb  = Kb  + (size_t)4 * 1024 * 1024;  // 4M (untransposed)
    unsigned short* Vtb = Vb  + (size_t)4 * 1024 * 1024;  // 4M
    unsigned short* Ob  = Vtb + (size_t)4 * 1024 * 1024;  // 4M  (56 MB total)

    // Split-K partials alias Qb..Vtb (32 MB, dead after flash):
    // P0 = Qb..Kb (16 MB), P1 = Vb..Vtb (16 MB), contiguous.
    float* Pp = (float*)Qb;

    fused_convert_kernel<<<dim3(6144), 256, 0, stream>>>(
        x, Xb, w_qkv, Wqt, w_proj, Wpt);

    gemm_qkv_mfma<<<dim3(3 * D_MODEL / 128, BATCH * SEQ / 128), 256, 0, stream>>>(
        Xb, Wqt, Qb, Kb, Vb);

    v_transpose<<<dim3(SEQ / 64, BATCH * N_HEADS), 256, 0, stream>>>(Vb, Vtb);

    flash_attn_kernel<<<dim3(SEQ / 64 * BATCH * N_HEADS), 256, 0, stream>>>(
        Qb, Kb, Vtb, Ob);

    gemm_proj_splitk<<<dim3(D_MODEL / 128, BATCH * SEQ / 128, 2), 256, 0, stream>>>(
        Ob, Wpt, Pp);

    add_out_kernel<<<dim3(1024), 256, 0, stream>>>(Pp, out);
}